// Round 1
// baseline (1363.488 us; speedup 1.0000x reference)
//
#include <hip/hip_runtime.h>

// SubLinear: o[b,j] = sum_{i in segment j} x[b,i]*w[i] + bias[j]
// B=64, F=2^22, OUT=64. Memory-bound: 1.07 GB of x is the floor (~175us @6.3TB/s).
//
// Layout: 1024 blocks x 4096-feature chunks. Each block holds its w slice in
// registers for all 64 batch rows (w/seg read once from HBM). Segments are
// contiguous & sorted -> a chunk is "uniform" (1 segment) for ~994/1024 blocks,
// decided block-uniformly by two scalar loads (no divergence).

#define TPB 256
#define CHUNK 4096   // features per block (= TPB * 4 floats * 4 k-steps)
#define BG 4         // batch rows per inner pass

__global__ __launch_bounds__(TPB) void init_out_kernel(const float* __restrict__ bias,
                                                       float* __restrict__ out,
                                                       int n, int outf) {
    int i = blockIdx.x * TPB + threadIdx.x;
    if (i < n) out[i] = bias[i % outf];
}

__global__ __launch_bounds__(TPB) void sublinear_kernel(
    const float* __restrict__ x,
    const float* __restrict__ w,
    const int*   __restrict__ seg,
    float*       __restrict__ out,
    int F, int B) {
    const int base = blockIdx.x * CHUNK;
    const int tid  = threadIdx.x;

    // Per-thread strided-coalesced element set: e(k,c) = base + k*1024 + tid*4 + c
    // (lane i reads float4 at lane*16B -> perfect 1KB/instr coalescing)
    float4 wreg[4];
#pragma unroll
    for (int k = 0; k < 4; ++k)
        wreg[k] = *(const float4*)(w + base + k * (TPB * 4) + tid * 4);

    const int jLo = seg[base];
    const int jHi = seg[base + CHUNK - 1];

    if (jLo == jHi) {
        // ---------- uniform chunk fast path (~97% of blocks) ----------
        const int j = jLo;
        for (int b0 = 0; b0 < B; b0 += BG) {
            float run[BG] = {0.f, 0.f, 0.f, 0.f};
#pragma unroll
            for (int k = 0; k < 4; ++k) {
                const int off = base + k * (TPB * 4) + tid * 4;
#pragma unroll
                for (int u = 0; u < BG; ++u) {
                    float4 xv = *(const float4*)(x + (size_t)(b0 + u) * F + off);
                    run[u] += xv.x * wreg[k].x + xv.y * wreg[k].y +
                              xv.z * wreg[k].z + xv.w * wreg[k].w;
                }
            }
            // 64-wide butterfly reduce per wave
#pragma unroll
            for (int sh = 32; sh > 0; sh >>= 1) {
#pragma unroll
                for (int u = 0; u < BG; ++u) run[u] += __shfl_xor(run[u], sh, 64);
            }
            if ((tid & 63) == 0) {
#pragma unroll
                for (int u = 0; u < BG; ++u)
                    atomicAdd(&out[(size_t)(b0 + u) * 64 + j], run[u]);
            }
        }
    } else {
        // ---------- boundary chunk slow path (~30 blocks) ----------
        __shared__ float acc[BG * 64];   // acc[u][j]
        int4 sreg[4];
#pragma unroll
        for (int k = 0; k < 4; ++k)
            sreg[k] = *(const int4*)(seg + base + k * (TPB * 4) + tid * 4);

        for (int b0 = 0; b0 < B; b0 += BG) {
            acc[tid] = 0.f;              // BG*64 == TPB
            __syncthreads();

            float run[BG] = {0.f, 0.f, 0.f, 0.f};
            int cur = sreg[0].x;
#pragma unroll
            for (int k = 0; k < 4; ++k) {
                const int off = base + k * (TPB * 4) + tid * 4;
                float4 xv[BG];
#pragma unroll
                for (int u = 0; u < BG; ++u)
                    xv[u] = *(const float4*)(x + (size_t)(b0 + u) * F + off);
                const int   sarr[4] = {sreg[k].x, sreg[k].y, sreg[k].z, sreg[k].w};
                const float warr[4] = {wreg[k].x, wreg[k].y, wreg[k].z, wreg[k].w};
#pragma unroll
                for (int c = 0; c < 4; ++c) {
                    const int s = sarr[c];
                    if (s != cur) {      // segment transition: flush runs
#pragma unroll
                        for (int u = 0; u < BG; ++u) {
                            atomicAdd(&acc[u * 64 + cur], run[u]);
                            run[u] = 0.f;
                        }
                        cur = s;
                    }
#pragma unroll
                    for (int u = 0; u < BG; ++u)
                        run[u] += ((const float*)&xv[u])[c] * warr[c];
                }
            }
#pragma unroll
            for (int u = 0; u < BG; ++u) atomicAdd(&acc[u * 64 + cur], run[u]);
            __syncthreads();
            {
                const int u = tid >> 6, j = tid & 63;
                if (j >= jLo && j <= jHi)
                    atomicAdd(&out[(size_t)(b0 + u) * 64 + j], acc[tid]);
            }
            __syncthreads();
        }
    }
}

// Generic fallback for a non-multiple-of-CHUNK tail (not hit at F=2^22).
__global__ __launch_bounds__(TPB) void remainder_kernel(
    const float* __restrict__ x, const float* __restrict__ w,
    const int* __restrict__ seg, float* __restrict__ out,
    int F, int B, int start) {
    int i = start + blockIdx.x * TPB + threadIdx.x;
    if (i >= F) return;
    const float wv = w[i];
    const int   s  = seg[i];
    for (int b = 0; b < B; ++b)
        atomicAdd(&out[(size_t)b * 64 + s], x[(size_t)b * F + i] * wv);
}

extern "C" void kernel_launch(void* const* d_in, const int* in_sizes, int n_in,
                              void* d_out, int out_size, void* d_ws, size_t ws_size,
                              hipStream_t stream) {
    const float* x    = (const float*)d_in[0];
    const float* w    = (const float*)d_in[1];
    const float* bias = (const float*)d_in[2];
    const int*   seg  = (const int*)d_in[3];
    float*       out  = (float*)d_out;

    const int F    = in_sizes[1];            // 4194304
    const int B    = in_sizes[0] / F;        // 64
    const int OUTF = in_sizes[2];            // 64

    // d_out is re-poisoned before every call: materialize bias first.
    init_out_kernel<<<(out_size + TPB - 1) / TPB, TPB, 0, stream>>>(bias, out, out_size, OUTF);

    const int nChunks = F / CHUNK;           // 1024
    sublinear_kernel<<<nChunks, TPB, 0, stream>>>(x, w, seg, out, F, B);

    const int rem = F - nChunks * CHUNK;     // 0 for this shape
    if (rem > 0)
        remainder_kernel<<<(rem + TPB - 1) / TPB, TPB, 0, stream>>>(x, w, seg, out, F, B, nChunks * CHUNK);
}

// Round 2
// 1355.928 us; speedup vs baseline: 1.0056x; 1.0056x over previous
//
#include <hip/hip_runtime.h>

// SubLinear: o[b,j] = sum_{i in segment j} x[b,i]*w[i] + bias[j]
// B=64, F=2^22, OUT=64. Memory-bound: 1.07 GB of x -> ~176us floor @6.3TB/s.
//
// Grid: 1024 chunks x SPLITB batch-halves = 2048 blocks (8/CU). Each block
// stages its 4096-feature w slice in registers, streams 32 batch rows in
// groups of BG=8 (32 float4 loads in flight/thread). Segments are contiguous
// & sorted -> block-uniform fast path when seg[base]==seg[base+CHUNK-1]
// (~97% of blocks). Reduction: pairwise lane-merge (10 shuffles / 8 rows vs
// 48 naive), then one diverged atomic instr covers 8 rows.

#define TPB 256
#define CHUNK 4096   // features per block (= TPB * 4 floats * 4 k-steps)
#define BG 8         // batch rows per inner pass
#define SPLITB 2     // batch split across blocks

__global__ __launch_bounds__(TPB) void init_out_kernel(const float* __restrict__ bias,
                                                       float* __restrict__ out,
                                                       int n, int outf) {
    int i = blockIdx.x * TPB + threadIdx.x;
    if (i < n) out[i] = bias[i % outf];
}

__global__ __launch_bounds__(TPB) void sublinear_kernel(
    const float* __restrict__ x,
    const float* __restrict__ w,
    const int*   __restrict__ seg,
    float*       __restrict__ out,
    int F, int B) {
    const int base     = blockIdx.x * CHUNK;
    const int tid      = threadIdx.x;
    const int lane     = tid & 63;
    const int rows     = B / SPLITB;            // 32
    const int rowStart = blockIdx.y * rows;

    float4 wreg[4];
#pragma unroll
    for (int k = 0; k < 4; ++k)
        wreg[k] = *(const float4*)(w + base + k * (TPB * 4) + tid * 4);

    const int jLo = seg[base];
    const int jHi = seg[base + CHUNK - 1];

    if (jLo == jHi) {
        // ---------- uniform chunk fast path ----------
        const int j = jLo;
        for (int b0 = rowStart; b0 < rowStart + rows; b0 += BG) {
            float run[BG];
#pragma unroll
            for (int u = 0; u < BG; ++u) run[u] = 0.f;
#pragma unroll
            for (int k = 0; k < 4; ++k) {
                const int off = base + k * (TPB * 4) + tid * 4;
#pragma unroll
                for (int u = 0; u < BG; ++u) {
                    float4 xv = *(const float4*)(x + (size_t)(b0 + u) * F + off);
                    run[u] += xv.x * wreg[k].x + xv.y * wreg[k].y +
                              xv.z * wreg[k].z + xv.w * wreg[k].w;
                }
            }
            // pairwise merge: 8 per-row partials -> row (b0 + (lane&7)) in one reg
            float m[4];
#pragma unroll
            for (int v = 0; v < 4; ++v) {
                float keep = (lane & 1) ? run[2 * v + 1] : run[2 * v];
                float send = (lane & 1) ? run[2 * v]     : run[2 * v + 1];
                m[v] = keep + __shfl_xor(send, 1, 64);
            }
            float n2[2];
#pragma unroll
            for (int v = 0; v < 2; ++v) {
                float keep = (lane & 2) ? m[2 * v + 1] : m[2 * v];
                float send = (lane & 2) ? m[2 * v]     : m[2 * v + 1];
                n2[v] = keep + __shfl_xor(send, 2, 64);
            }
            float p;
            {
                float keep = (lane & 4) ? n2[1] : n2[0];
                float send = (lane & 4) ? n2[0] : n2[1];
                p = keep + __shfl_xor(send, 4, 64);
            }
            p += __shfl_xor(p, 8, 64);
            p += __shfl_xor(p, 16, 64);
            p += __shfl_xor(p, 32, 64);
            // every lane holds the full sum for row b0 + (lane&7)
            if (lane < BG)
                atomicAdd(&out[(size_t)(b0 + lane) * 64 + j], p);
        }
    } else {
        // ---------- boundary chunk slow path (~126 of 2048 blocks) ----------
        __shared__ float acc[BG * 64];          // acc[u][j]
        int4 sreg[4];
#pragma unroll
        for (int k = 0; k < 4; ++k)
            sreg[k] = *(const int4*)(seg + base + k * (TPB * 4) + tid * 4);

        for (int b0 = rowStart; b0 < rowStart + rows; b0 += BG) {
#pragma unroll
            for (int t = 0; t < (BG * 64) / TPB; ++t) acc[tid + t * TPB] = 0.f;
            __syncthreads();

            float run[BG];
#pragma unroll
            for (int u = 0; u < BG; ++u) run[u] = 0.f;
            int cur = sreg[0].x;
#pragma unroll
            for (int k = 0; k < 4; ++k) {
                const int off = base + k * (TPB * 4) + tid * 4;
                float4 xv[BG];
#pragma unroll
                for (int u = 0; u < BG; ++u)
                    xv[u] = *(const float4*)(x + (size_t)(b0 + u) * F + off);
                const int   sarr[4] = {sreg[k].x, sreg[k].y, sreg[k].z, sreg[k].w};
                const float warr[4] = {wreg[k].x, wreg[k].y, wreg[k].z, wreg[k].w};
#pragma unroll
                for (int c = 0; c < 4; ++c) {
                    const int s = sarr[c];
                    if (s != cur) {             // segment transition: flush runs
#pragma unroll
                        for (int u = 0; u < BG; ++u) {
                            atomicAdd(&acc[u * 64 + cur], run[u]);
                            run[u] = 0.f;
                        }
                        cur = s;
                    }
#pragma unroll
                    for (int u = 0; u < BG; ++u)
                        run[u] += ((const float*)&xv[u])[c] * warr[c];
                }
            }
#pragma unroll
            for (int u = 0; u < BG; ++u) atomicAdd(&acc[u * 64 + cur], run[u]);
            __syncthreads();
#pragma unroll
            for (int t = 0; t < (BG * 64) / TPB; ++t) {
                const int idx = tid + t * TPB;
                const int u = idx >> 6, j = idx & 63;
                if (j >= jLo && j <= jHi)
                    atomicAdd(&out[(size_t)(b0 + u) * 64 + j], acc[idx]);
            }
            __syncthreads();
        }
    }
}

// Generic fallback for a non-multiple-of-CHUNK tail (not hit at F=2^22).
__global__ __launch_bounds__(TPB) void remainder_kernel(
    const float* __restrict__ x, const float* __restrict__ w,
    const int* __restrict__ seg, float* __restrict__ out,
    int F, int B, int start) {
    int i = start + blockIdx.x * TPB + threadIdx.x;
    if (i >= F) return;
    const float wv = w[i];
    const int   s  = seg[i];
    for (int b = 0; b < B; ++b)
        atomicAdd(&out[(size_t)b * 64 + s], x[(size_t)b * F + i] * wv);
}

extern "C" void kernel_launch(void* const* d_in, const int* in_sizes, int n_in,
                              void* d_out, int out_size, void* d_ws, size_t ws_size,
                              hipStream_t stream) {
    const float* x    = (const float*)d_in[0];
    const float* w    = (const float*)d_in[1];
    const float* bias = (const float*)d_in[2];
    const int*   seg  = (const int*)d_in[3];
    float*       out  = (float*)d_out;

    const int F    = in_sizes[1];            // 4194304
    const int B    = in_sizes[0] / F;        // 64
    const int OUTF = in_sizes[2];            // 64

    // d_out is re-poisoned before every call: materialize bias first.
    init_out_kernel<<<(out_size + TPB - 1) / TPB, TPB, 0, stream>>>(bias, out, out_size, OUTF);

    const int nChunks = F / CHUNK;           // 1024
    dim3 grid(nChunks, SPLITB);
    sublinear_kernel<<<grid, TPB, 0, stream>>>(x, w, seg, out, F, B);

    const int rem = F - nChunks * CHUNK;     // 0 for this shape
    if (rem > 0)
        remainder_kernel<<<(rem + TPB - 1) / TPB, TPB, 0, stream>>>(x, w, seg, out, F, B, nChunks * CHUNK);
}